// Round 13
// baseline (137.716 us; speedup 1.0000x reference)
//
#include <hip/hip_runtime.h>
#include <stdint.h>

#define AS1 __attribute__((address_space(1)))
#define AS3 __attribute__((address_space(3)))

typedef float f32x4 __attribute__((ext_vector_type(4)));
typedef __bf16 bf16x8 __attribute__((ext_vector_type(8)));
typedef uint32_t u32x2 __attribute__((ext_vector_type(2)));
typedef unsigned short u16;
typedef u16 u16x8 __attribute__((ext_vector_type(8)));

// fp32 -> bf16, round-to-nearest-even
__device__ __forceinline__ unsigned short f2bf(float f) {
    uint32_t x = __float_as_uint(f);
    x += 0x7FFFu + ((x >> 16) & 1u);
    return (unsigned short)(x >> 16);
}
__device__ __forceinline__ float bf2f(unsigned short u) {
    return __uint_as_float((uint32_t)u << 16);
}

__device__ __forceinline__ void gload_lds16(const void* g, void* l) {
    __builtin_amdgcn_global_load_lds((const AS1 void*)g, (AS3 void*)l, 16, 0, 0);
}

// ---------------------------------------------------------------------------
// Kernel 0: WT[n][f] = bf16(W[f][n]).  W is [256][256] fp32 row-major.
// ---------------------------------------------------------------------------
__global__ __launch_bounds__(256) void wt_kernel(const float* __restrict__ W,
                                                 unsigned short* __restrict__ WT) {
    __shared__ float tile[32][33];
    const int bf = blockIdx.x & 7;
    const int bn = blockIdx.x >> 3;
    const int t = threadIdx.x;
    const int c = t & 31, r = t >> 5;
#pragma unroll
    for (int i = 0; i < 4; ++i)
        tile[r + i * 8][c] = W[(bf * 32 + r + i * 8) * 256 + bn * 32 + c];
    __syncthreads();
#pragma unroll
    for (int i = 0; i < 4; ++i)
        WT[(bn * 32 + r + i * 8) * 256 + bf * 32 + c] = f2bf(tile[c][r + i * 8]);
}

// ---------------------------------------------------------------------------
// gemm1 (r11-verified incl. coalesced epilogue): dkT[n][m] = bf16(data@W)^T.
// Tile BM=32, BN=256, BK=64; 4 waves.
// ---------------------------------------------------------------------------
template <int LDA, int LDB, int KSTEPS>
__global__ __launch_bounds__(256) void gemm1_kernel(const float* __restrict__ A,
                                                    const unsigned short* __restrict__ B,
                                                    unsigned short* __restrict__ dkT) {
    __shared__ unsigned short Alds[32 * 64];
    __shared__ unsigned short Blds[256 * 64];  // reused as [256][40] u16 epilogue

    const int t = threadIdx.x;
    const int w = t >> 6;
    const int l = t & 63;
    const int m0 = blockIdx.x * 32;

    const int ar = t >> 3;
    const int kq = t & 7;
    const float* gA = A + (size_t)(m0 + ar) * LDA + kq * 4;
    char* aw0 = (char*)Alds + ((ar * 128 + kq * 8) ^ ((ar & 7) << 4));
    char* aw1 = (char*)Alds + ((ar * 128 + 64 + kq * 8) ^ ((ar & 7) << 4));

    const int nr_base = w * 64 + (l >> 3);
    const int c16 = l & 7;

    f32x4 acc[2][4];
#pragma unroll
    for (int i = 0; i < 2; ++i)
#pragma unroll
        for (int j = 0; j < 4; ++j) acc[i][j] = (f32x4){0.f, 0.f, 0.f, 0.f};

    for (int step = 0; step < KSTEPS; ++step) {
        const int k0 = step * 64;
        __syncthreads();
#pragma unroll
        for (int i = 0; i < 8; ++i) {
            const int nr = nr_base + i * 8;
            const unsigned short* src =
                B + (size_t)nr * LDB + k0 + ((c16 ^ (nr & 7)) << 3);
            gload_lds16(src, (char*)Blds + (w * 512 + i * 64) * 16);
        }
        const f32x4 v0 = *(const f32x4*)(gA + k0);
        const f32x4 v1 = *(const f32x4*)(gA + k0 + 32);
        uint32_t p0 = (uint32_t)f2bf(v0.x) | ((uint32_t)f2bf(v0.y) << 16);
        uint32_t p1 = (uint32_t)f2bf(v0.z) | ((uint32_t)f2bf(v0.w) << 16);
        uint32_t p2 = (uint32_t)f2bf(v1.x) | ((uint32_t)f2bf(v1.y) << 16);
        uint32_t p3 = (uint32_t)f2bf(v1.z) | ((uint32_t)f2bf(v1.w) << 16);
        ((uint32_t*)aw0)[0] = p0;
        ((uint32_t*)aw0)[1] = p1;
        ((uint32_t*)aw1)[0] = p2;
        ((uint32_t*)aw1)[1] = p3;
        __syncthreads();
#pragma unroll
        for (int kh = 0; kh < 2; ++kh) {
            const int koffb = kh * 64 + ((l >> 4) << 4);
            bf16x8 af[2], bv[4];
#pragma unroll
            for (int im = 0; im < 2; ++im) {
                const int r = im * 16 + (l & 15);
                af[im] = *(const bf16x8*)((const char*)Alds +
                                          ((r * 128 + koffb) ^ ((r & 7) << 4)));
            }
#pragma unroll
            for (int jn = 0; jn < 4; ++jn) {
                const int n = w * 64 + jn * 16 + (l & 15);
                bv[jn] = *(const bf16x8*)((const char*)Blds +
                                          ((n * 128 + koffb) ^ ((n & 7) << 4)));
            }
#pragma unroll
            for (int im = 0; im < 2; ++im)
#pragma unroll
                for (int jn = 0; jn < 4; ++jn)
                    acc[im][jn] = __builtin_amdgcn_mfma_f32_16x16x32_bf16(
                        af[im], bv[jn], acc[im][jn], 0, 0, 0);
        }
    }

    // ---- epilogue: stage C^T in LDS [256][40] u16, stream 64B/thread rows.
    __syncthreads();
    u16* T = (u16*)Blds;
#pragma unroll
    for (int im = 0; im < 2; ++im) {
        const int mq = im * 16 + ((l >> 4) << 2);
#pragma unroll
        for (int jn = 0; jn < 4; ++jn) {
            const int n = w * 64 + jn * 16 + (l & 15);
            u32x2 pk;
            pk[0] = (uint32_t)f2bf(acc[im][jn][0]) |
                    ((uint32_t)f2bf(acc[im][jn][1]) << 16);
            pk[1] = (uint32_t)f2bf(acc[im][jn][2]) |
                    ((uint32_t)f2bf(acc[im][jn][3]) << 16);
            *(u32x2*)((char*)T + n * 80 + mq * 2) = pk;
        }
    }
    __syncthreads();
    {
        const int n = t;
        const char* src = (const char*)T + n * 80;
        char* dst = (char*)(dkT + (size_t)n * 8192 + m0);
#pragma unroll
        for (int i = 0; i < 4; ++i)
            *(f32x4*)(dst + i * 16) = *(const f32x4*)(src + i * 16);
    }
}

// ---------------------------------------------------------------------------
// gemm2: out = adj @ dk.  BM=64, BN=128, BK=64, 256 threads = 4 waves (2x2),
// wave tile 32x64, acc[2][4].  LDS 24 KB -> 6 resident blocks/CU (the r3
// lever, extended: more barrier-decoupled load streams per CU).
// Grid = 128 mtiles x 2 ntiles x KSPLIT.  Maps: A staging = r8/r11 verbatim;
// B staging = gemm1's 256-thr map (rows 0..127); reads/epilogue unchanged.
// KSPLIT>1: bf16 partials (all splits) to Pws[ks]; KSPLIT==1: relu to Out0.
// ---------------------------------------------------------------------------
template <int KSPLIT>
__global__ __launch_bounds__(256) void gemm2_kernel(const float* __restrict__ A,
                                                    const unsigned short* __restrict__ B,
                                                    float* __restrict__ Out0,
                                                    u16* __restrict__ Pws) {
    __shared__ unsigned short Alds[64 * 64];   // 8 KB bf16, swizzled rows
    __shared__ unsigned short Blds[128 * 64];  // 16 KB bf16, swizzled rows

    const int t = threadIdx.x;
    const int w = t >> 6;       // wave 0..3
    const int l = t & 63;
    const int wr = w >> 1;      // 0..1 (32-row slice)
    const int wc = w & 1;       // 0..1 (64-col slice)
    const int q = l >> 4;
    const int li = l & 15;

    const int bid = blockIdx.x;
    const int ks = bid % KSPLIT;
    const int nt = (bid / KSPLIT) & 1;
    const int mtile = bid / (2 * KSPLIT);
    const int m0 = mtile * 64;
    const int n0 = nt * 128;
    const int kbase = ks * (8192 / KSPLIT);
    constexpr int KSTEPS = (8192 / KSPLIT) / 64;

    // A staging (r8/r11 verbatim): round j covers rows [j*16, j*16+16);
    // thread t -> row jr = t>>4, fp32 16B-chunk jc = t&15 (coalesced).
    const int jr = t >> 4;
    const int jc = t & 15;
    const float* gA = A + (size_t)(m0 + jr) * 8192 + kbase + jc * 4;

    // B staging (gemm1 map, 128 rows): issue i covers rows nr = i*32 + (t>>3),
    // 8 threads/row, chunk c16 = t&7, source pre-XOR'd ((t>>3)&7 invariant).
    const int br0 = t >> 3;  // 0..31
    const int c16 = t & 7;
    const unsigned short* gB =
        B + (size_t)(n0 + br0) * 8192 + kbase + ((c16 ^ (br0 & 7)) << 3);

    f32x4 acc[2][4];
#pragma unroll
    for (int i = 0; i < 2; ++i)
#pragma unroll
        for (int j = 0; j < 4; ++j) acc[i][j] = (f32x4){0.f, 0.f, 0.f, 0.f};

    for (int step = 0; step < KSTEPS; ++step) {
        const int k0 = step * 64;
        __syncthreads();  // previous compute done -> LDS reusable
        // ---- B tile: [128 n][64 k] bf16 via global_load_lds (4 issues)
#pragma unroll
        for (int i = 0; i < 4; ++i)
            gload_lds16(gB + (size_t)i * 32 * 8192 + k0,
                        (char*)Blds + (i * 256 + t) * 16);
        // ---- A tile: [64 m][64 k] fp32 -> bf16, 4 rounds of 16 rows
#pragma unroll
        for (int j = 0; j < 4; ++j) {
            const f32x4 v = __builtin_nontemporal_load(
                (const f32x4*)(gA + (size_t)j * 16 * 8192 + k0));
            const int r = j * 16 + jr;
            const int p = (jc >> 1) ^ (r & 7);
            u32x2 pk;
            pk[0] = (uint32_t)f2bf(v.x) | ((uint32_t)f2bf(v.y) << 16);
            pk[1] = (uint32_t)f2bf(v.z) | ((uint32_t)f2bf(v.w) << 16);
            *(u32x2*)((char*)Alds + r * 128 + p * 16 + (jc & 1) * 8) = pk;
        }
        __syncthreads();  // drains vmcnt/lgkmcnt: tiles ready
        // ---- compute: 2 k-halves x (2 m x 4 n) fragments
#pragma unroll
        for (int kh = 0; kh < 2; ++kh) {
            const int koffb = kh * 64 + (q << 4);
            bf16x8 af[2], bv[4];
#pragma unroll
            for (int im = 0; im < 2; ++im) {
                const int r = wr * 32 + im * 16 + li;
                af[im] = *(const bf16x8*)((const char*)Alds +
                                          ((r * 128 + koffb) ^ ((r & 7) << 4)));
            }
#pragma unroll
            for (int jn = 0; jn < 4; ++jn) {
                const int n = wc * 64 + jn * 16 + li;
                bv[jn] = *(const bf16x8*)((const char*)Blds +
                                          ((n * 128 + koffb) ^ ((n & 7) << 4)));
            }
#pragma unroll
            for (int im = 0; im < 2; ++im)
#pragma unroll
                for (int jn = 0; jn < 4; ++jn)
                    acc[im][jn] = __builtin_amdgcn_mfma_f32_16x16x32_bf16(
                        af[im], bv[jn], acc[im][jn], 0, 0, 0);
        }
    }

    // ---- epilogue.  C/D frag: col = l&15, row = (l>>4)*4 + reg  [m89]
    if (KSPLIT == 1) {
#pragma unroll
        for (int im = 0; im < 2; ++im) {
            const int row0 = m0 + wr * 32 + im * 16 + (q << 2);
#pragma unroll
            for (int jn = 0; jn < 4; ++jn) {
                const int col = n0 + wc * 64 + jn * 16 + li;
#pragma unroll
                for (int r = 0; r < 4; ++r) {
                    const float v = acc[im][jn][r];
                    Out0[(size_t)(row0 + r) * 256 + col] = v > 0.f ? v : 0.f;
                }
            }
        }
    } else {
        u16* Pb = Pws + (size_t)ks * (8192 * 256);
#pragma unroll
        for (int im = 0; im < 2; ++im) {
            const int row0 = m0 + wr * 32 + im * 16 + (q << 2);
#pragma unroll
            for (int jn = 0; jn < 4; ++jn) {
                const int col = n0 + wc * 64 + jn * 16 + li;
#pragma unroll
                for (int r = 0; r < 4; ++r)
                    Pb[(size_t)(row0 + r) * 256 + col] = f2bf(acc[im][jn][r]);
            }
        }
    }
}

// ---------------------------------------------------------------------------
// out = relu( sum_{s<S} bf16 P[s] )  over 8192*256, 8 elems/thread.
// ---------------------------------------------------------------------------
template <int S>
__global__ __launch_bounds__(256) void reduce_relu_kernel(float* __restrict__ out,
                                                          const u16* __restrict__ P) {
    const size_t i = (size_t)blockIdx.x * 256 + threadIdx.x;  // 262144 groups
    float s0 = 0, s1 = 0, s2 = 0, s3 = 0, s4 = 0, s5 = 0, s6 = 0, s7 = 0;
#pragma unroll
    for (int s = 0; s < S; ++s) {
        const u16x8 v = ((const u16x8*)(P + (size_t)s * (8192 * 256)))[i];
        s0 += bf2f(v[0]); s1 += bf2f(v[1]); s2 += bf2f(v[2]); s3 += bf2f(v[3]);
        s4 += bf2f(v[4]); s5 += bf2f(v[5]); s6 += bf2f(v[6]); s7 += bf2f(v[7]);
    }
    f32x4 lo, hi;
    lo.x = s0 > 0.f ? s0 : 0.f; lo.y = s1 > 0.f ? s1 : 0.f;
    lo.z = s2 > 0.f ? s2 : 0.f; lo.w = s3 > 0.f ? s3 : 0.f;
    hi.x = s4 > 0.f ? s4 : 0.f; hi.y = s5 > 0.f ? s5 : 0.f;
    hi.z = s6 > 0.f ? s6 : 0.f; hi.w = s7 > 0.f ? s7 : 0.f;
    ((f32x4*)out)[2 * i] = lo;
    ((f32x4*)out)[2 * i + 1] = hi;
}

// ---------------------------------------------------------------------------
extern "C" void kernel_launch(void* const* d_in, const int* in_sizes, int n_in,
                              void* d_out, int out_size, void* d_ws, size_t ws_size,
                              hipStream_t stream) {
    const float* data = (const float*)d_in[0];  // [1,8192,256] fp32
    const float* adj = (const float*)d_in[1];   // [1,8192,8192] fp32
    const float* Wk = (const float*)d_in[2];    // [256,256] fp32
    float* out = (float*)d_out;                 // [1,8192,256] fp32

    unsigned short* WT = (unsigned short*)d_ws;                     // 128 KB
    unsigned short* dkT = (unsigned short*)((char*)d_ws + 131072);  // 4 MB bf16
    u16* Pb = (u16*)((char*)d_ws + 131072 + 4194304);               // bf16 partials

    const size_t base_need = 131072 + 4194304;
    const size_t part_bytes = (size_t)8192 * 256 * 2;  // 4 MB per split (bf16)

    // 1) W^T in bf16
    wt_kernel<<<64, 256, 0, stream>>>(Wk, WT);
    // 2) dkT[n][m] = (data @ W)^T   : M=8192, N=256, K=256
    gemm1_kernel<256, 256, 4><<<256, 256, 0, stream>>>(data, WT, dkT);
    // 3) out = relu(adj @ dk)       : M=8192, N=256, K=8192
    //    BM=64/BN=128, LDS 24 KB -> 6 blocks/CU; KSPLIT=4 -> grid 1024.
    if (ws_size >= base_need + 4 * part_bytes) {
        gemm2_kernel<4><<<1024, 256, 0, stream>>>(adj, dkT, out, Pb);
        reduce_relu_kernel<4><<<1024, 256, 0, stream>>>(out, Pb);
    } else if (ws_size >= base_need + 2 * part_bytes) {
        gemm2_kernel<2><<<512, 256, 0, stream>>>(adj, dkT, out, Pb);
        reduce_relu_kernel<2><<<1024, 256, 0, stream>>>(out, Pb);
    } else {
        gemm2_kernel<1><<<256, 256, 0, stream>>>(adj, dkT, out, nullptr);
    }
}

// Round 14
// 99.014 us; speedup vs baseline: 1.3909x; 1.3909x over previous
//
#include <hip/hip_runtime.h>
#include <stdint.h>

#define AS1 __attribute__((address_space(1)))
#define AS3 __attribute__((address_space(3)))

typedef float f32x4 __attribute__((ext_vector_type(4)));
typedef __bf16 bf16x8 __attribute__((ext_vector_type(8)));
typedef uint32_t u32x2 __attribute__((ext_vector_type(2)));
typedef unsigned short u16;
typedef u16 u16x8 __attribute__((ext_vector_type(8)));

// fp32 -> bf16, round-to-nearest-even
__device__ __forceinline__ unsigned short f2bf(float f) {
    uint32_t x = __float_as_uint(f);
    x += 0x7FFFu + ((x >> 16) & 1u);
    return (unsigned short)(x >> 16);
}
__device__ __forceinline__ float bf2f(unsigned short u) {
    return __uint_as_float((uint32_t)u << 16);
}

__device__ __forceinline__ void gload_lds16(const void* g, void* l) {
    __builtin_amdgcn_global_load_lds((const AS1 void*)g, (AS3 void*)l, 16, 0, 0);
}

// ---------------------------------------------------------------------------
// Kernel 0: WT[n][f] = bf16(W[f][n]).  W is [256][256] fp32 row-major.
// ---------------------------------------------------------------------------
__global__ __launch_bounds__(256) void wt_kernel(const float* __restrict__ W,
                                                 unsigned short* __restrict__ WT) {
    __shared__ float tile[32][33];
    const int bf = blockIdx.x & 7;
    const int bn = blockIdx.x >> 3;
    const int t = threadIdx.x;
    const int c = t & 31, r = t >> 5;
#pragma unroll
    for (int i = 0; i < 4; ++i)
        tile[r + i * 8][c] = W[(bf * 32 + r + i * 8) * 256 + bn * 32 + c];
    __syncthreads();
#pragma unroll
    for (int i = 0; i < 4; ++i)
        WT[(bn * 32 + r + i * 8) * 256 + bf * 32 + c] = f2bf(tile[c][r + i * 8]);
}

// ---------------------------------------------------------------------------
// gemm1 (r11-verified incl. coalesced epilogue): dkT[n][m] = bf16(data@W)^T.
// Tile BM=32, BN=256, BK=64; 4 waves.
// ---------------------------------------------------------------------------
template <int LDA, int LDB, int KSTEPS>
__global__ __launch_bounds__(256) void gemm1_kernel(const float* __restrict__ A,
                                                    const unsigned short* __restrict__ B,
                                                    unsigned short* __restrict__ dkT) {
    __shared__ unsigned short Alds[32 * 64];
    __shared__ unsigned short Blds[256 * 64];  // reused as [256][40] u16 epilogue

    const int t = threadIdx.x;
    const int w = t >> 6;
    const int l = t & 63;
    const int m0 = blockIdx.x * 32;

    const int ar = t >> 3;
    const int kq = t & 7;
    const float* gA = A + (size_t)(m0 + ar) * LDA + kq * 4;
    char* aw0 = (char*)Alds + ((ar * 128 + kq * 8) ^ ((ar & 7) << 4));
    char* aw1 = (char*)Alds + ((ar * 128 + 64 + kq * 8) ^ ((ar & 7) << 4));

    const int nr_base = w * 64 + (l >> 3);
    const int c16 = l & 7;

    f32x4 acc[2][4];
#pragma unroll
    for (int i = 0; i < 2; ++i)
#pragma unroll
        for (int j = 0; j < 4; ++j) acc[i][j] = (f32x4){0.f, 0.f, 0.f, 0.f};

    for (int step = 0; step < KSTEPS; ++step) {
        const int k0 = step * 64;
        __syncthreads();
#pragma unroll
        for (int i = 0; i < 8; ++i) {
            const int nr = nr_base + i * 8;
            const unsigned short* src =
                B + (size_t)nr * LDB + k0 + ((c16 ^ (nr & 7)) << 3);
            gload_lds16(src, (char*)Blds + (w * 512 + i * 64) * 16);
        }
        const f32x4 v0 = *(const f32x4*)(gA + k0);
        const f32x4 v1 = *(const f32x4*)(gA + k0 + 32);
        uint32_t p0 = (uint32_t)f2bf(v0.x) | ((uint32_t)f2bf(v0.y) << 16);
        uint32_t p1 = (uint32_t)f2bf(v0.z) | ((uint32_t)f2bf(v0.w) << 16);
        uint32_t p2 = (uint32_t)f2bf(v1.x) | ((uint32_t)f2bf(v1.y) << 16);
        uint32_t p3 = (uint32_t)f2bf(v1.z) | ((uint32_t)f2bf(v1.w) << 16);
        ((uint32_t*)aw0)[0] = p0;
        ((uint32_t*)aw0)[1] = p1;
        ((uint32_t*)aw1)[0] = p2;
        ((uint32_t*)aw1)[1] = p3;
        __syncthreads();
#pragma unroll
        for (int kh = 0; kh < 2; ++kh) {
            const int koffb = kh * 64 + ((l >> 4) << 4);
            bf16x8 af[2], bv[4];
#pragma unroll
            for (int im = 0; im < 2; ++im) {
                const int r = im * 16 + (l & 15);
                af[im] = *(const bf16x8*)((const char*)Alds +
                                          ((r * 128 + koffb) ^ ((r & 7) << 4)));
            }
#pragma unroll
            for (int jn = 0; jn < 4; ++jn) {
                const int n = w * 64 + jn * 16 + (l & 15);
                bv[jn] = *(const bf16x8*)((const char*)Blds +
                                          ((n * 128 + koffb) ^ ((n & 7) << 4)));
            }
#pragma unroll
            for (int im = 0; im < 2; ++im)
#pragma unroll
                for (int jn = 0; jn < 4; ++jn)
                    acc[im][jn] = __builtin_amdgcn_mfma_f32_16x16x32_bf16(
                        af[im], bv[jn], acc[im][jn], 0, 0, 0);
        }
    }

    // ---- epilogue: stage C^T in LDS [256][40] u16, stream 64B/thread rows.
    __syncthreads();
    u16* T = (u16*)Blds;
#pragma unroll
    for (int im = 0; im < 2; ++im) {
        const int mq = im * 16 + ((l >> 4) << 2);
#pragma unroll
        for (int jn = 0; jn < 4; ++jn) {
            const int n = w * 64 + jn * 16 + (l & 15);
            u32x2 pk;
            pk[0] = (uint32_t)f2bf(acc[im][jn][0]) |
                    ((uint32_t)f2bf(acc[im][jn][1]) << 16);
            pk[1] = (uint32_t)f2bf(acc[im][jn][2]) |
                    ((uint32_t)f2bf(acc[im][jn][3]) << 16);
            *(u32x2*)((char*)T + n * 80 + mq * 2) = pk;
        }
    }
    __syncthreads();
    {
        const int n = t;
        const char* src = (const char*)T + n * 80;
        char* dst = (char*)(dkT + (size_t)n * 8192 + m0);
#pragma unroll
        for (int i = 0; i < 4; ++i)
            *(f32x4*)(dst + i * 16) = *(const f32x4*)(src + i * 16);
    }
}

// ---------------------------------------------------------------------------
// gemm2 (r9 geometry, VGPR cap REMOVED): out = adj @ dk.
// BM=128, BN=256, BK=64, 512 threads = 8 waves (2x4), wave tile 64x64
// (acc[4][4]).  Single-buffered 2-barrier loop; LDS 48 KB.  Halves B-panel
// re-staging traffic vs BM=64 (512 -> 256 MB of L2->LDS bytes).
// r9 lesson: NO min-waves launch bound (it caps VGPR -> scratch spill; r9's
// VGPR_Count=40 disaster).  Code identical to r9's correctness-passing gemm2
// except the launch bound and nontemporal A loads.
// KSPLIT>1: bf16 partials to Pws[ks]; KSPLIT==1: fp32 relu to Out0.
// ---------------------------------------------------------------------------
template <int KSPLIT>
__global__ __launch_bounds__(512) void gemm2_kernel(const float* __restrict__ A,
                                                    const unsigned short* __restrict__ B,
                                                    float* __restrict__ Out0,
                                                    u16* __restrict__ Pws) {
    __shared__ unsigned short Alds[128 * 64];  // 16 KB bf16, swizzled rows
    __shared__ unsigned short Blds[256 * 64];  // 32 KB bf16, swizzled rows

    const int t = threadIdx.x;  // 0..511
    const int w = t >> 6;       // wave 0..7
    const int l = t & 63;
    const int wr = w >> 2;      // 0..1  (64-row slice)
    const int wc = w & 3;       // 0..3  (64-col slice)
    const int q = l >> 4;
    const int li = l & 15;
    const int mtile = blockIdx.x / KSPLIT;
    const int ks = blockIdx.x % KSPLIT;
    const int m0 = mtile * 128;
    const int kbase = ks * (8192 / KSPLIT);
    constexpr int KSTEPS = (8192 / KSPLIT) / 64;

    // A staging: round j covers rows [j*32, j*32+32); thread t -> row-in-round
    // rr0 = t>>4, fp32 16B-chunk jc = t&15 (coalesced 256B/row).
    const int rr0 = t >> 4;
    const int jc = t & 15;
    const float* gA = A + (size_t)(m0 + rr0) * 8192 + kbase + jc * 4;
    const int ap = (jc >> 1) ^ (rr0 & 7);  // loop-invariant (32 % 8 == 0)
    char* const awbase = (char*)Alds + rr0 * 128 + ap * 16 + (jc & 1) * 8;

    // B staging (gemm1's map, 512 thr): issue i covers rows nr = i*64 + (t>>3),
    // 8 threads/row, chunk c16 = t&7, source pre-XOR'd.
    const int br0 = t >> 3;
    const int c16 = t & 7;
    const unsigned short* gB =
        B + (size_t)br0 * 8192 + kbase + ((c16 ^ (br0 & 7)) << 3);

    f32x4 acc[4][4];
#pragma unroll
    for (int i = 0; i < 4; ++i)
#pragma unroll
        for (int j = 0; j < 4; ++j) acc[i][j] = (f32x4){0.f, 0.f, 0.f, 0.f};

    for (int step = 0; step < KSTEPS; ++step) {
        const int k0 = step * 64;
        __syncthreads();  // previous compute done -> LDS reusable
        // ---- B tile: [256 n][64 k] bf16 via global_load_lds (4 issues)
#pragma unroll
        for (int i = 0; i < 4; ++i)
            gload_lds16(gB + (size_t)i * 64 * 8192 + k0,
                        (char*)Blds + (i * 512 + w * 64) * 16);
        // ---- A tile: [128 m][64 k] fp32 -> bf16, 4 rounds of 32 rows
#pragma unroll
        for (int j = 0; j < 4; ++j) {
            const f32x4 v = __builtin_nontemporal_load(
                (const f32x4*)(gA + (size_t)j * 32 * 8192 + k0));
            u32x2 pk;
            pk[0] = (uint32_t)f2bf(v.x) | ((uint32_t)f2bf(v.y) << 16);
            pk[1] = (uint32_t)f2bf(v.z) | ((uint32_t)f2bf(v.w) << 16);
            *(u32x2*)(awbase + j * 32 * 128) = pk;
        }
        __syncthreads();  // drains vmcnt/lgkmcnt: tiles ready
        // ---- compute: 2 k-halves x (4 m x 4 n) fragments
#pragma unroll
        for (int kh = 0; kh < 2; ++kh) {
            const int koffb = kh * 64 + (q << 4);
            bf16x8 af[4], bv[4];
#pragma unroll
            for (int im = 0; im < 4; ++im) {
                const int r = wr * 64 + im * 16 + li;
                af[im] = *(const bf16x8*)((const char*)Alds +
                                          ((r * 128 + koffb) ^ ((r & 7) << 4)));
            }
#pragma unroll
            for (int jn = 0; jn < 4; ++jn) {
                const int n = wc * 64 + jn * 16 + li;
                bv[jn] = *(const bf16x8*)((const char*)Blds +
                                          ((n * 128 + koffb) ^ ((n & 7) << 4)));
            }
#pragma unroll
            for (int im = 0; im < 4; ++im)
#pragma unroll
                for (int jn = 0; jn < 4; ++jn)
                    acc[im][jn] = __builtin_amdgcn_mfma_f32_16x16x32_bf16(
                        af[im], bv[jn], acc[im][jn], 0, 0, 0);
        }
    }

    // ---- epilogue.  C/D frag: col = l&15, row = (l>>4)*4 + reg  [m89]
    if (KSPLIT == 1) {
#pragma unroll
        for (int im = 0; im < 4; ++im) {
            const int row0 = m0 + wr * 64 + im * 16 + (q << 2);
#pragma unroll
            for (int jn = 0; jn < 4; ++jn) {
                const int col = wc * 64 + jn * 16 + li;
#pragma unroll
                for (int r = 0; r < 4; ++r) {
                    const float v = acc[im][jn][r];
                    Out0[(size_t)(row0 + r) * 256 + col] = v > 0.f ? v : 0.f;
                }
            }
        }
    } else {
        u16* Pb = Pws + (size_t)ks * (8192 * 256);
#pragma unroll
        for (int im = 0; im < 4; ++im) {
            const int row0 = m0 + wr * 64 + im * 16 + (q << 2);
#pragma unroll
            for (int jn = 0; jn < 4; ++jn) {
                const int col = wc * 64 + jn * 16 + li;
#pragma unroll
                for (int r = 0; r < 4; ++r)
                    Pb[(size_t)(row0 + r) * 256 + col] = f2bf(acc[im][jn][r]);
            }
        }
    }
}

// ---------------------------------------------------------------------------
// out = relu( sum_{s<S} bf16 P[s] )  over 8192*256, 8 elems/thread.
// ---------------------------------------------------------------------------
template <int S>
__global__ __launch_bounds__(256) void reduce_relu_kernel(float* __restrict__ out,
                                                          const u16* __restrict__ P) {
    const size_t i = (size_t)blockIdx.x * 256 + threadIdx.x;  // 262144 groups
    float s0 = 0, s1 = 0, s2 = 0, s3 = 0, s4 = 0, s5 = 0, s6 = 0, s7 = 0;
#pragma unroll
    for (int s = 0; s < S; ++s) {
        const u16x8 v = ((const u16x8*)(P + (size_t)s * (8192 * 256)))[i];
        s0 += bf2f(v[0]); s1 += bf2f(v[1]); s2 += bf2f(v[2]); s3 += bf2f(v[3]);
        s4 += bf2f(v[4]); s5 += bf2f(v[5]); s6 += bf2f(v[6]); s7 += bf2f(v[7]);
    }
    f32x4 lo, hi;
    lo.x = s0 > 0.f ? s0 : 0.f; lo.y = s1 > 0.f ? s1 : 0.f;
    lo.z = s2 > 0.f ? s2 : 0.f; lo.w = s3 > 0.f ? s3 : 0.f;
    hi.x = s4 > 0.f ? s4 : 0.f; hi.y = s5 > 0.f ? s5 : 0.f;
    hi.z = s6 > 0.f ? s6 : 0.f; hi.w = s7 > 0.f ? s7 : 0.f;
    ((f32x4*)out)[2 * i] = lo;
    ((f32x4*)out)[2 * i + 1] = hi;
}

// ---------------------------------------------------------------------------
extern "C" void kernel_launch(void* const* d_in, const int* in_sizes, int n_in,
                              void* d_out, int out_size, void* d_ws, size_t ws_size,
                              hipStream_t stream) {
    const float* data = (const float*)d_in[0];  // [1,8192,256] fp32
    const float* adj = (const float*)d_in[1];   // [1,8192,8192] fp32
    const float* Wk = (const float*)d_in[2];    // [256,256] fp32
    float* out = (float*)d_out;                 // [1,8192,256] fp32

    unsigned short* WT = (unsigned short*)d_ws;                     // 128 KB
    unsigned short* dkT = (unsigned short*)((char*)d_ws + 131072);  // 4 MB bf16
    u16* Pb = (u16*)((char*)d_ws + 131072 + 4194304);               // bf16 partials

    const size_t base_need = 131072 + 4194304;
    const size_t part_bytes = (size_t)8192 * 256 * 2;  // 4 MB per split (bf16)

    // 1) W^T in bf16
    wt_kernel<<<64, 256, 0, stream>>>(Wk, WT);
    // 2) dkT[n][m] = (data @ W)^T   : M=8192, N=256, K=256
    gemm1_kernel<256, 256, 4><<<256, 256, 0, stream>>>(data, WT, dkT);
    // 3) out = relu(adj @ dk)       : M=8192, N=256, K=8192
    //    BM=128/BN=256, KSPLIT=8 -> grid 512.
    if (ws_size >= base_need + 8 * part_bytes) {
        gemm2_kernel<8><<<512, 512, 0, stream>>>(adj, dkT, out, Pb);
        reduce_relu_kernel<8><<<1024, 256, 0, stream>>>(out, Pb);
    } else if (ws_size >= base_need + 2 * part_bytes) {
        gemm2_kernel<2><<<128, 512, 0, stream>>>(adj, dkT, out, Pb);
        reduce_relu_kernel<2><<<1024, 256, 0, stream>>>(out, Pb);
    } else {
        gemm2_kernel<1><<<64, 512, 0, stream>>>(adj, dkT, out, nullptr);
    }
}

// Round 15
// 97.809 us; speedup vs baseline: 1.4080x; 1.0123x over previous
//
#include <hip/hip_runtime.h>
#include <stdint.h>

#define AS1 __attribute__((address_space(1)))
#define AS3 __attribute__((address_space(3)))

typedef float f32x4 __attribute__((ext_vector_type(4)));
typedef __bf16 bf16x8 __attribute__((ext_vector_type(8)));
typedef uint32_t u32x2 __attribute__((ext_vector_type(2)));
typedef unsigned short u16;
typedef u16 u16x8 __attribute__((ext_vector_type(8)));

// fp32 -> bf16, round-to-nearest-even
__device__ __forceinline__ unsigned short f2bf(float f) {
    uint32_t x = __float_as_uint(f);
    x += 0x7FFFu + ((x >> 16) & 1u);
    return (unsigned short)(x >> 16);
}
__device__ __forceinline__ float bf2f(unsigned short u) {
    return __uint_as_float((uint32_t)u << 16);
}

__device__ __forceinline__ void gload_lds16(const void* g, void* l) {
    __builtin_amdgcn_global_load_lds((const AS1 void*)g, (AS3 void*)l, 16, 0, 0);
}

// ---------------------------------------------------------------------------
// Kernel 0: WT[n][f] = bf16(W[f][n]).  W is [256][256] fp32 row-major.
// ---------------------------------------------------------------------------
__global__ __launch_bounds__(256) void wt_kernel(const float* __restrict__ W,
                                                 unsigned short* __restrict__ WT) {
    __shared__ float tile[32][33];
    const int bf = blockIdx.x & 7;
    const int bn = blockIdx.x >> 3;
    const int t = threadIdx.x;
    const int c = t & 31, r = t >> 5;
#pragma unroll
    for (int i = 0; i < 4; ++i)
        tile[r + i * 8][c] = W[(bf * 32 + r + i * 8) * 256 + bn * 32 + c];
    __syncthreads();
#pragma unroll
    for (int i = 0; i < 4; ++i)
        WT[(bn * 32 + r + i * 8) * 256 + bf * 32 + c] = f2bf(tile[c][r + i * 8]);
}

// ---------------------------------------------------------------------------
// gemm1 (r11-verified incl. coalesced epilogue): dkT[n][m] = bf16(data@W)^T.
// Tile BM=32, BN=256, BK=64; 4 waves.
// ---------------------------------------------------------------------------
template <int LDA, int LDB, int KSTEPS>
__global__ __launch_bounds__(256) void gemm1_kernel(const float* __restrict__ A,
                                                    const unsigned short* __restrict__ B,
                                                    unsigned short* __restrict__ dkT) {
    __shared__ unsigned short Alds[32 * 64];
    __shared__ unsigned short Blds[256 * 64];  // reused as [256][40] u16 epilogue

    const int t = threadIdx.x;
    const int w = t >> 6;
    const int l = t & 63;
    const int m0 = blockIdx.x * 32;

    const int ar = t >> 3;
    const int kq = t & 7;
    const float* gA = A + (size_t)(m0 + ar) * LDA + kq * 4;
    char* aw0 = (char*)Alds + ((ar * 128 + kq * 8) ^ ((ar & 7) << 4));
    char* aw1 = (char*)Alds + ((ar * 128 + 64 + kq * 8) ^ ((ar & 7) << 4));

    const int nr_base = w * 64 + (l >> 3);
    const int c16 = l & 7;

    f32x4 acc[2][4];
#pragma unroll
    for (int i = 0; i < 2; ++i)
#pragma unroll
        for (int j = 0; j < 4; ++j) acc[i][j] = (f32x4){0.f, 0.f, 0.f, 0.f};

    for (int step = 0; step < KSTEPS; ++step) {
        const int k0 = step * 64;
        __syncthreads();
#pragma unroll
        for (int i = 0; i < 8; ++i) {
            const int nr = nr_base + i * 8;
            const unsigned short* src =
                B + (size_t)nr * LDB + k0 + ((c16 ^ (nr & 7)) << 3);
            gload_lds16(src, (char*)Blds + (w * 512 + i * 64) * 16);
        }
        const f32x4 v0 = *(const f32x4*)(gA + k0);
        const f32x4 v1 = *(const f32x4*)(gA + k0 + 32);
        uint32_t p0 = (uint32_t)f2bf(v0.x) | ((uint32_t)f2bf(v0.y) << 16);
        uint32_t p1 = (uint32_t)f2bf(v0.z) | ((uint32_t)f2bf(v0.w) << 16);
        uint32_t p2 = (uint32_t)f2bf(v1.x) | ((uint32_t)f2bf(v1.y) << 16);
        uint32_t p3 = (uint32_t)f2bf(v1.z) | ((uint32_t)f2bf(v1.w) << 16);
        ((uint32_t*)aw0)[0] = p0;
        ((uint32_t*)aw0)[1] = p1;
        ((uint32_t*)aw1)[0] = p2;
        ((uint32_t*)aw1)[1] = p3;
        __syncthreads();
#pragma unroll
        for (int kh = 0; kh < 2; ++kh) {
            const int koffb = kh * 64 + ((l >> 4) << 4);
            bf16x8 af[2], bv[4];
#pragma unroll
            for (int im = 0; im < 2; ++im) {
                const int r = im * 16 + (l & 15);
                af[im] = *(const bf16x8*)((const char*)Alds +
                                          ((r * 128 + koffb) ^ ((r & 7) << 4)));
            }
#pragma unroll
            for (int jn = 0; jn < 4; ++jn) {
                const int n = w * 64 + jn * 16 + (l & 15);
                bv[jn] = *(const bf16x8*)((const char*)Blds +
                                          ((n * 128 + koffb) ^ ((n & 7) << 4)));
            }
#pragma unroll
            for (int im = 0; im < 2; ++im)
#pragma unroll
                for (int jn = 0; jn < 4; ++jn)
                    acc[im][jn] = __builtin_amdgcn_mfma_f32_16x16x32_bf16(
                        af[im], bv[jn], acc[im][jn], 0, 0, 0);
        }
    }

    // ---- epilogue: stage C^T in LDS [256][40] u16, stream 64B/thread rows.
    __syncthreads();
    u16* T = (u16*)Blds;
#pragma unroll
    for (int im = 0; im < 2; ++im) {
        const int mq = im * 16 + ((l >> 4) << 2);
#pragma unroll
        for (int jn = 0; jn < 4; ++jn) {
            const int n = w * 64 + jn * 16 + (l & 15);
            u32x2 pk;
            pk[0] = (uint32_t)f2bf(acc[im][jn][0]) |
                    ((uint32_t)f2bf(acc[im][jn][1]) << 16);
            pk[1] = (uint32_t)f2bf(acc[im][jn][2]) |
                    ((uint32_t)f2bf(acc[im][jn][3]) << 16);
            *(u32x2*)((char*)T + n * 80 + mq * 2) = pk;
        }
    }
    __syncthreads();
    {
        const int n = t;
        const char* src = (const char*)T + n * 80;
        char* dst = (char*)(dkT + (size_t)n * 8192 + m0);
#pragma unroll
        for (int i = 0; i < 4; ++i)
            *(f32x4*)(dst + i * 16) = *(const f32x4*)(src + i * 16);
    }
}

// ---------------------------------------------------------------------------
// gemm2 (r14 structure, nt REMOVED): out = adj @ dk.
// BM=128, BN=256, BK=64, 512 threads = 8 waves (2x4), wave tile 64x64
// (acc[4][4]).  Single-buffered 2-barrier loop; LDS 48 KB.
// r15 delta: adj loads are PLAIN (not nontemporal) — r1/r5 counters show
// Infinity Cache absorbs ~45% of adj across graph replays (FETCH 147 vs
// 268 MB); nt loads defeated that retention (r9: FETCH 300 MB).
// KSPLIT>1: bf16 partials to Pws[ks]; KSPLIT==1: fp32 relu to Out0.
// NO min-waves launch bound (r9 lesson: it caps VGPR -> scratch spill).
// ---------------------------------------------------------------------------
template <int KSPLIT>
__global__ __launch_bounds__(512) void gemm2_kernel(const float* __restrict__ A,
                                                    const unsigned short* __restrict__ B,
                                                    float* __restrict__ Out0,
                                                    u16* __restrict__ Pws) {
    __shared__ unsigned short Alds[128 * 64];  // 16 KB bf16, swizzled rows
    __shared__ unsigned short Blds[256 * 64];  // 32 KB bf16, swizzled rows

    const int t = threadIdx.x;  // 0..511
    const int w = t >> 6;       // wave 0..7
    const int l = t & 63;
    const int wr = w >> 2;      // 0..1  (64-row slice)
    const int wc = w & 3;       // 0..3  (64-col slice)
    const int q = l >> 4;
    const int li = l & 15;
    const int mtile = blockIdx.x / KSPLIT;
    const int ks = blockIdx.x % KSPLIT;
    const int m0 = mtile * 128;
    const int kbase = ks * (8192 / KSPLIT);
    constexpr int KSTEPS = (8192 / KSPLIT) / 64;

    // A staging: round j covers rows [j*32, j*32+32); thread t -> row-in-round
    // rr0 = t>>4, fp32 16B-chunk jc = t&15 (coalesced 256B/row).
    const int rr0 = t >> 4;
    const int jc = t & 15;
    const float* gA = A + (size_t)(m0 + rr0) * 8192 + kbase + jc * 4;
    const int ap = (jc >> 1) ^ (rr0 & 7);  // loop-invariant (32 % 8 == 0)
    char* const awbase = (char*)Alds + rr0 * 128 + ap * 16 + (jc & 1) * 8;

    // B staging (gemm1's map, 512 thr): issue i covers rows nr = i*64 + (t>>3),
    // 8 threads/row, chunk c16 = t&7, source pre-XOR'd.
    const int br0 = t >> 3;
    const int c16 = t & 7;
    const unsigned short* gB =
        B + (size_t)br0 * 8192 + kbase + ((c16 ^ (br0 & 7)) << 3);

    f32x4 acc[4][4];
#pragma unroll
    for (int i = 0; i < 4; ++i)
#pragma unroll
        for (int j = 0; j < 4; ++j) acc[i][j] = (f32x4){0.f, 0.f, 0.f, 0.f};

    for (int step = 0; step < KSTEPS; ++step) {
        const int k0 = step * 64;
        __syncthreads();  // previous compute done -> LDS reusable
        // ---- B tile: [256 n][64 k] bf16 via global_load_lds (4 issues)
#pragma unroll
        for (int i = 0; i < 4; ++i)
            gload_lds16(gB + (size_t)i * 64 * 8192 + k0,
                        (char*)Blds + (i * 512 + w * 64) * 16);
        // ---- A tile: [128 m][64 k] fp32 -> bf16, 4 rounds of 32 rows
        //      PLAIN loads (L3 retains adj across replays — r1/r5 evidence).
#pragma unroll
        for (int j = 0; j < 4; ++j) {
            const f32x4 v = *(const f32x4*)(gA + (size_t)j * 32 * 8192 + k0);
            u32x2 pk;
            pk[0] = (uint32_t)f2bf(v.x) | ((uint32_t)f2bf(v.y) << 16);
            pk[1] = (uint32_t)f2bf(v.z) | ((uint32_t)f2bf(v.w) << 16);
            *(u32x2*)(awbase + j * 32 * 128) = pk;
        }
        __syncthreads();  // drains vmcnt/lgkmcnt: tiles ready
        // ---- compute: 2 k-halves x (4 m x 4 n) fragments
#pragma unroll
        for (int kh = 0; kh < 2; ++kh) {
            const int koffb = kh * 64 + (q << 4);
            bf16x8 af[4], bv[4];
#pragma unroll
            for (int im = 0; im < 4; ++im) {
                const int r = wr * 64 + im * 16 + li;
                af[im] = *(const bf16x8*)((const char*)Alds +
                                          ((r * 128 + koffb) ^ ((r & 7) << 4)));
            }
#pragma unroll
            for (int jn = 0; jn < 4; ++jn) {
                const int n = wc * 64 + jn * 16 + li;
                bv[jn] = *(const bf16x8*)((const char*)Blds +
                                          ((n * 128 + koffb) ^ ((n & 7) << 4)));
            }
#pragma unroll
            for (int im = 0; im < 4; ++im)
#pragma unroll
                for (int jn = 0; jn < 4; ++jn)
                    acc[im][jn] = __builtin_amdgcn_mfma_f32_16x16x32_bf16(
                        af[im], bv[jn], acc[im][jn], 0, 0, 0);
        }
    }

    // ---- epilogue.  C/D frag: col = l&15, row = (l>>4)*4 + reg  [m89]
    if (KSPLIT == 1) {
#pragma unroll
        for (int im = 0; im < 4; ++im) {
            const int row0 = m0 + wr * 64 + im * 16 + (q << 2);
#pragma unroll
            for (int jn = 0; jn < 4; ++jn) {
                const int col = wc * 64 + jn * 16 + li;
#pragma unroll
                for (int r = 0; r < 4; ++r) {
                    const float v = acc[im][jn][r];
                    Out0[(size_t)(row0 + r) * 256 + col] = v > 0.f ? v : 0.f;
                }
            }
        }
    } else {
        u16* Pb = Pws + (size_t)ks * (8192 * 256);
#pragma unroll
        for (int im = 0; im < 4; ++im) {
            const int row0 = m0 + wr * 64 + im * 16 + (q << 2);
#pragma unroll
            for (int jn = 0; jn < 4; ++jn) {
                const int col = wc * 64 + jn * 16 + li;
#pragma unroll
                for (int r = 0; r < 4; ++r)
                    Pb[(size_t)(row0 + r) * 256 + col] = f2bf(acc[im][jn][r]);
            }
        }
    }
}

// ---------------------------------------------------------------------------
// out = relu( sum_{s<S} bf16 P[s] )  over 8192*256, 8 elems/thread.
// ---------------------------------------------------------------------------
template <int S>
__global__ __launch_bounds__(256) void reduce_relu_kernel(float* __restrict__ out,
                                                          const u16* __restrict__ P) {
    const size_t i = (size_t)blockIdx.x * 256 + threadIdx.x;  // 262144 groups
    float s0 = 0, s1 = 0, s2 = 0, s3 = 0, s4 = 0, s5 = 0, s6 = 0, s7 = 0;
#pragma unroll
    for (int s = 0; s < S; ++s) {
        const u16x8 v = ((const u16x8*)(P + (size_t)s * (8192 * 256)))[i];
        s0 += bf2f(v[0]); s1 += bf2f(v[1]); s2 += bf2f(v[2]); s3 += bf2f(v[3]);
        s4 += bf2f(v[4]); s5 += bf2f(v[5]); s6 += bf2f(v[6]); s7 += bf2f(v[7]);
    }
    f32x4 lo, hi;
    lo.x = s0 > 0.f ? s0 : 0.f; lo.y = s1 > 0.f ? s1 : 0.f;
    lo.z = s2 > 0.f ? s2 : 0.f; lo.w = s3 > 0.f ? s3 : 0.f;
    hi.x = s4 > 0.f ? s4 : 0.f; hi.y = s5 > 0.f ? s5 : 0.f;
    hi.z = s6 > 0.f ? s6 : 0.f; hi.w = s7 > 0.f ? s7 : 0.f;
    ((f32x4*)out)[2 * i] = lo;
    ((f32x4*)out)[2 * i + 1] = hi;
}

// ---------------------------------------------------------------------------
extern "C" void kernel_launch(void* const* d_in, const int* in_sizes, int n_in,
                              void* d_out, int out_size, void* d_ws, size_t ws_size,
                              hipStream_t stream) {
    const float* data = (const float*)d_in[0];  // [1,8192,256] fp32
    const float* adj = (const float*)d_in[1];   // [1,8192,8192] fp32
    const float* Wk = (const float*)d_in[2];    // [256,256] fp32
    float* out = (float*)d_out;                 // [1,8192,256] fp32

    unsigned short* WT = (unsigned short*)d_ws;                     // 128 KB
    unsigned short* dkT = (unsigned short*)((char*)d_ws + 131072);  // 4 MB bf16
    u16* Pb = (u16*)((char*)d_ws + 131072 + 4194304);               // bf16 partials

    const size_t base_need = 131072 + 4194304;
    const size_t part_bytes = (size_t)8192 * 256 * 2;  // 4 MB per split (bf16)

    // 1) W^T in bf16
    wt_kernel<<<64, 256, 0, stream>>>(Wk, WT);
    // 2) dkT[n][m] = (data @ W)^T   : M=8192, N=256, K=256
    gemm1_kernel<256, 256, 4><<<256, 256, 0, stream>>>(data, WT, dkT);
    // 3) out = relu(adj @ dk)       : M=8192, N=256, K=8192
    //    BM=128/BN=256, KSPLIT=8 -> grid 512.
    if (ws_size >= base_need + 8 * part_bytes) {
        gemm2_kernel<8><<<512, 512, 0, stream>>>(adj, dkT, out, Pb);
        reduce_relu_kernel<8><<<1024, 256, 0, stream>>>(out, Pb);
    } else if (ws_size >= base_need + 2 * part_bytes) {
        gemm2_kernel<2><<<128, 512, 0, stream>>>(adj, dkT, out, Pb);
        reduce_relu_kernel<2><<<1024, 256, 0, stream>>>(out, Pb);
    } else {
        gemm2_kernel<1><<<64, 512, 0, stream>>>(adj, dkT, out, nullptr);
    }
}